// Round 1
// baseline (406.286 us; speedup 1.0000x reference)
//
#include <hip/hip_runtime.h>

// Problem constants (fixed by the reference setup_inputs)
#define T_ 4096
#define D_ 4096
#define O_ 4096
#define L_ 32
#define R_ 8

constexpr int BM = 128, BN = 128, BK = 32;

typedef __bf16 bf16x8 __attribute__((ext_vector_type(8)));
typedef float f32x4 __attribute__((ext_vector_type(4)));

// fp32 -> bf16 round-to-nearest-even
__device__ __forceinline__ unsigned short f2bf(float f) {
    unsigned int u = __float_as_uint(f);
    u = (u + 0x7fffu + ((u >> 16) & 1u)) >> 16;
    return (unsigned short)u;
}

// async global->LDS, 16B per lane. LDS dest = wave-uniform base + lane*16.
__device__ __forceinline__ void load_lds16(const void* g, void* l) {
    __builtin_amdgcn_global_load_lds((__attribute__((address_space(1))) void*)g,
                                     (__attribute__((address_space(3))) void*)l,
                                     16, 0, 0);
}

// ---------------------------------------------------------------------------
// Kernel 1: fp32 -> bf16 conversion (one float4 / thread, exact grid)
// ---------------------------------------------------------------------------
__global__ __launch_bounds__(256) void cvt_kernel(const float* __restrict__ src,
                                                  unsigned short* __restrict__ dst) {
    const int i = (blockIdx.x * 256 + threadIdx.x) * 4;
    float4 v = *(const float4*)&src[i];
    ushort4 o;
    o.x = f2bf(v.x); o.y = f2bf(v.y); o.z = f2bf(v.z); o.w = f2bf(v.w);
    *(ushort4*)&dst[i] = o;
}

// ---------------------------------------------------------------------------
// Kernel 2: LoRA shrink  shrink[t,r] = dot(x[t,:], A[lora[t],0,r,:]) (fp32)
// one wave per token; 4 tokens per 256-thread block
// ---------------------------------------------------------------------------
__global__ __launch_bounds__(256) void shrink_kernel(const float* __restrict__ x,
                                                     const float* __restrict__ lora_a,
                                                     const int* __restrict__ tli,
                                                     float* __restrict__ shrink) {
    const int wave = threadIdx.x >> 6;
    const int lane = threadIdx.x & 63;
    const int t = blockIdx.x * 4 + wave;
    const int idx = tli[t];
    if (idx < 0) {                 // wave-uniform branch
        if (lane < R_) shrink[t * R_ + lane] = 0.0f;
        return;
    }
    const float* xr = x + (size_t)t * D_;
    const float* ab = lora_a + (size_t)idx * R_ * D_;
    float acc[R_];
#pragma unroll
    for (int r = 0; r < R_; ++r) acc[r] = 0.0f;

    for (int d = lane * 4; d < D_; d += 64 * 4) {
        float4 xv = *(const float4*)&xr[d];
#pragma unroll
        for (int r = 0; r < R_; ++r) {
            float4 av = *(const float4*)&ab[r * D_ + d];
            acc[r] += xv.x * av.x + xv.y * av.y + xv.z * av.z + xv.w * av.w;
        }
    }
#pragma unroll
    for (int r = 0; r < R_; ++r) {
        float v = acc[r];
        for (int off = 32; off > 0; off >>= 1) v += __shfl_xor(v, off, 64);
        if (lane == r) shrink[t * R_ + r] = v;
    }
}

// ---------------------------------------------------------------------------
// Kernel 3: bf16 MFMA GEMM (m97 structure) + fused LoRA expand/bias epilogue
//   C[t,o] = sum_k xb[t,k]*wb[o,k] + base_bias[o]
//            + (idx>=0 ? bias_st[idx,o] + dot8(shrink[t,:], lora_b[idx,o,:]) : 0)
// 128x128 tile, BK=32, 4 waves in 2x2, each wave 64x64 (4x4 MFMA tiles)
// ---------------------------------------------------------------------------
__global__ __launch_bounds__(256) void gemm_lora(const short* __restrict__ xb,
                                                 const short* __restrict__ wb,
                                                 const float* __restrict__ base_bias,
                                                 const float* __restrict__ lora_b,
                                                 const float* __restrict__ bias_st,
                                                 const int* __restrict__ tli,
                                                 const float* __restrict__ shrink,
                                                 float* __restrict__ out) {
    __shared__ short As[BM * BK];   // row-major [128][32] bf16 = 8 KB
    __shared__ short Bs[BN * BK];   // row-major [128][32] bf16 = 8 KB

    const int tid = threadIdx.x;
    const int lane = tid & 63;
    const int quad = lane >> 4;
    const int l15 = lane & 15;
    const int wave = tid >> 6;
    const int wm = wave >> 1;       // wave row (0..1)
    const int wn = wave & 1;        // wave col (0..1)

    const int bn = blockIdx.x & 31;
    const int bm = blockIdx.x >> 5;
    const int t0 = bm * BM;
    const int o0 = bn * BN;

    // staging: 512 chunks of 16B per tile; chunk c -> row c>>2, col (c&3)*8
    const int c0 = tid, c1 = tid + 256;
    const short* ag0 = xb + (size_t)(t0 + (c0 >> 2)) * D_ + (c0 & 3) * 8;
    const short* ag1 = xb + (size_t)(t0 + (c1 >> 2)) * D_ + (c1 & 3) * 8;
    const short* bg0 = wb + (size_t)(o0 + (c0 >> 2)) * D_ + (c0 & 3) * 8;
    const short* bg1 = wb + (size_t)(o0 + (c1 >> 2)) * D_ + (c1 & 3) * 8;
    // wave-uniform LDS bases (HW adds lane*16 bytes)
    short* al0 = &As[(wave << 6) * 8];
    short* al1 = &As[((wave << 6) + 256) * 8];
    short* bl0 = &Bs[(wave << 6) * 8];
    short* bl1 = &Bs[((wave << 6) + 256) * 8];

    f32x4 acc[4][4];
#pragma unroll
    for (int mi = 0; mi < 4; ++mi)
#pragma unroll
        for (int ni = 0; ni < 4; ++ni)
            acc[mi][ni] = f32x4{0.f, 0.f, 0.f, 0.f};

    const int arow = wm * 64 + l15;   // A-frag row in As
    const int brow = wn * 64 + l15;   // B-frag row in Bs

    for (int k0 = 0; k0 < D_; k0 += BK) {
        load_lds16(ag0 + k0, al0);
        load_lds16(ag1 + k0, al1);
        load_lds16(bg0 + k0, bl0);
        load_lds16(bg1 + k0, bl1);
        __syncthreads();   // drains vmcnt -> tiles visible

        bf16x8 af[4], bfr[4];
#pragma unroll
        for (int i = 0; i < 4; ++i) {
            af[i]  = *(const bf16x8*)&As[(arow + i * 16) * BK + quad * 8];
            bfr[i] = *(const bf16x8*)&Bs[(brow + i * 16) * BK + quad * 8];
        }
#pragma unroll
        for (int mi = 0; mi < 4; ++mi)
#pragma unroll
            for (int ni = 0; ni < 4; ++ni)
                acc[mi][ni] = __builtin_amdgcn_mfma_f32_16x16x32_bf16(
                    af[mi], bfr[ni], acc[mi][ni], 0, 0, 0);
        __syncthreads();   // all waves done reading before next overwrite
    }

    // Epilogue: C/D layout col = lane&15, row = quad*4 + reg
    const int col_base = o0 + wn * 64 + l15;
#pragma unroll
    for (int mi = 0; mi < 4; ++mi) {
#pragma unroll
        for (int reg = 0; reg < 4; ++reg) {
            const int row = t0 + wm * 64 + mi * 16 + quad * 4 + reg;
            const int idx = tli[row];
            const bool valid = (idx >= 0);
            float4 s0 = {0.f, 0.f, 0.f, 0.f}, s1 = {0.f, 0.f, 0.f, 0.f};
            if (valid) {
                s0 = *(const float4*)&shrink[row * R_];
                s1 = *(const float4*)&shrink[row * R_ + 4];
            }
#pragma unroll
            for (int ni = 0; ni < 4; ++ni) {
                const int col = col_base + ni * 16;
                float r = acc[mi][ni][reg] + base_bias[col];
                if (valid) {
                    const float* bp = &lora_b[((size_t)idx * O_ + col) * R_];
                    float4 b0 = *(const float4*)&bp[0];
                    float4 b1 = *(const float4*)&bp[4];
                    r += bias_st[(size_t)idx * O_ + col];
                    r += s0.x * b0.x + s0.y * b0.y + s0.z * b0.z + s0.w * b0.w +
                         s1.x * b1.x + s1.y * b1.y + s1.z * b1.z + s1.w * b1.w;
                }
                out[(size_t)row * O_ + col] = r;
            }
        }
    }
}

// ---------------------------------------------------------------------------
extern "C" void kernel_launch(void* const* d_in, const int* in_sizes, int n_in,
                              void* d_out, int out_size, void* d_ws, size_t ws_size,
                              hipStream_t stream) {
    const float* x    = (const float*)d_in[0];   // [T,D]
    const float* w    = (const float*)d_in[1];   // [O,D]
    const float* bb   = (const float*)d_in[2];   // [O]
    const float* la   = (const float*)d_in[3];   // [L,1,R,D]
    const float* lb   = (const float*)d_in[4];   // [L,1,O,R]
    const float* bs   = (const float*)d_in[5];   // [L,1,O]
    const int*   tli  = (const int*)d_in[6];     // [T]
    float* out = (float*)d_out;

    // workspace layout: xb (T*D bf16) | wb (O*D bf16) | shrink (T*R fp32)
    unsigned short* xb = (unsigned short*)d_ws;
    unsigned short* wb = xb + (size_t)T_ * D_;
    float* shrink = (float*)(wb + (size_t)O_ * D_);

    cvt_kernel<<<(T_ * (size_t)D_) / 1024, 256, 0, stream>>>(x, xb);
    cvt_kernel<<<(O_ * (size_t)D_) / 1024, 256, 0, stream>>>(w, wb);
    shrink_kernel<<<T_ / 4, 256, 0, stream>>>(x, la, tli, shrink);
    gemm_lora<<<(T_ / BM) * (O_ / BN), 256, 0, stream>>>(
        (const short*)xb, (const short*)wb, bb, lb, bs, tli, shrink, out);
}

// Round 2
// 366.544 us; speedup vs baseline: 1.1084x; 1.1084x over previous
//
#include <hip/hip_runtime.h>

// Problem constants (fixed by the reference setup_inputs)
#define T_ 4096
#define D_ 4096
#define O_ 4096
#define L_ 32
#define R_ 8

constexpr int BM = 128, BN = 128, BK = 64;

typedef __bf16 bf16x8 __attribute__((ext_vector_type(8)));
typedef float f32x4 __attribute__((ext_vector_type(4)));

// fp32 -> bf16 round-to-nearest-even
__device__ __forceinline__ unsigned short f2bf(float f) {
    unsigned int u = __float_as_uint(f);
    u = (u + 0x7fffu + ((u >> 16) & 1u)) >> 16;
    return (unsigned short)u;
}

// async global->LDS, 16B per lane. LDS dest = wave-uniform base + lane*16.
__device__ __forceinline__ void load_lds16(const void* g, void* l) {
    __builtin_amdgcn_global_load_lds((__attribute__((address_space(1))) void*)g,
                                     (__attribute__((address_space(3))) void*)l,
                                     16, 0, 0);
}

// ---------------------------------------------------------------------------
// Kernel 1: fp32 -> bf16 conversion for W (one float4 / thread, exact grid)
// ---------------------------------------------------------------------------
__global__ __launch_bounds__(256) void cvt_kernel(const float* __restrict__ src,
                                                  unsigned short* __restrict__ dst) {
    const int i = (blockIdx.x * 256 + threadIdx.x) * 4;
    float4 v = *(const float4*)&src[i];
    ushort4 o;
    o.x = f2bf(v.x); o.y = f2bf(v.y); o.z = f2bf(v.z); o.w = f2bf(v.w);
    *(ushort4*)&dst[i] = o;
}

// ---------------------------------------------------------------------------
// Kernel 2: fused  x fp32->bf16 conversion + LoRA shrink.
// One block per token. Reads x row once (16 KB), writes bf16 row (8 KB),
// and accumulates shrink[t,r] = dot(x[t,:], A[idx,0,r,:]) for r=0..7.
// ---------------------------------------------------------------------------
__global__ __launch_bounds__(256) void cvtx_shrink(const float* __restrict__ x,
                                                   const float* __restrict__ lora_a,
                                                   const int* __restrict__ tli,
                                                   unsigned short* __restrict__ xb,
                                                   float* __restrict__ shrink) {
    const int t = blockIdx.x;
    const int tid = threadIdx.x;
    const int lane = tid & 63;
    const int wave = tid >> 6;
    const int idx = tli[t];
    const float* xr = x + (size_t)t * D_;
    unsigned short* xo = xb + (size_t)t * D_;

    float acc[R_];
#pragma unroll
    for (int r = 0; r < R_; ++r) acc[r] = 0.0f;

    if (idx >= 0) {
        const float* ab = lora_a + (size_t)idx * R_ * D_;
#pragma unroll
        for (int j = 0; j < 4; ++j) {
            const int d = (j * 256 + tid) * 4;
            float4 v = *(const float4*)&xr[d];
            ushort4 o;
            o.x = f2bf(v.x); o.y = f2bf(v.y); o.z = f2bf(v.z); o.w = f2bf(v.w);
            *(ushort4*)&xo[d] = o;
#pragma unroll
            for (int r = 0; r < R_; ++r) {
                float4 a = *(const float4*)&ab[r * D_ + d];
                acc[r] += v.x * a.x + v.y * a.y + v.z * a.z + v.w * a.w;
            }
        }
    } else {
#pragma unroll
        for (int j = 0; j < 4; ++j) {
            const int d = (j * 256 + tid) * 4;
            float4 v = *(const float4*)&xr[d];
            ushort4 o;
            o.x = f2bf(v.x); o.y = f2bf(v.y); o.z = f2bf(v.z); o.w = f2bf(v.w);
            *(ushort4*)&xo[d] = o;
        }
    }

    // block reduction of acc[0..7]
    __shared__ float red[4][R_];
#pragma unroll
    for (int r = 0; r < R_; ++r) {
        float v = acc[r];
#pragma unroll
        for (int off = 32; off > 0; off >>= 1) v += __shfl_xor(v, off, 64);
        if (lane == 0) red[wave][r] = v;
    }
    __syncthreads();
    if (tid < R_) {
        float s = red[0][tid] + red[1][tid] + red[2][tid] + red[3][tid];
        shrink[t * R_ + tid] = (idx >= 0) ? s : 0.0f;
    }
}

// ---------------------------------------------------------------------------
// Kernel 3: bf16 MFMA GEMM, BK=64, XOR-swizzled LDS + fused LoRA epilogue.
// 128x128 tile, 4 waves in 2x2, each wave 64x64 (4x4 MFMA tiles), 32 MFMA
// per barrier pair. LDS physical layout: row-major [row][8 chunks of 16B],
// chunk cb of row r stored at slot (cb ^ (r&7)) -> 2-way banks on ds_read_b128.
// ---------------------------------------------------------------------------
__global__ __launch_bounds__(256) void gemm_lora(const short* __restrict__ xb,
                                                 const short* __restrict__ wb,
                                                 const float* __restrict__ base_bias,
                                                 const float* __restrict__ lora_b,
                                                 const float* __restrict__ bias_st,
                                                 const int* __restrict__ tli,
                                                 const float* __restrict__ shrink,
                                                 float* __restrict__ out) {
    __shared__ short As[BM * BK];   // 16 KB
    __shared__ short Bs[BN * BK];   // 16 KB

    const int tid = threadIdx.x;
    const int lane = tid & 63;
    const int quad = lane >> 4;
    const int l15 = lane & 15;
    const int wave = tid >> 6;
    const int wm = wave >> 1;       // wave row (0..1)
    const int wn = wave & 1;        // wave col (0..1)

    const int bn = blockIdx.x & 31;
    const int bm = blockIdx.x >> 5;
    const int t0 = bm * BM;
    const int o0 = bn * BN;

    // --- staging map: chunk c (0..1023) -> LDS offset c*16B.
    // chunk c covers row r=c>>3, logical col-block cb=(c&7)^(r&7) (XOR swizzle).
    // lane ℓ of wave w, issue j: c = j*256 + w*64 + ℓ  ->  r = j*32 + w*8 + (ℓ>>3),
    // cb = (ℓ&7)^(ℓ>>3)  (static per lane).
    const int lr = lane >> 3;
    const int lc = (lane & 7) ^ lr;
    const short* agl = xb + (size_t)(t0 + wave * 8 + lr) * D_ + lc * 8;
    const short* bgl = wb + (size_t)(o0 + wave * 8 + lr) * D_ + lc * 8;
    short* asl = &As[wave * 512];   // + j*2048 per issue; HW adds lane*8 shorts
    short* bsl = &Bs[wave * 512];

    f32x4 acc[4][4];
#pragma unroll
    for (int mi = 0; mi < 4; ++mi)
#pragma unroll
        for (int ni = 0; ni < 4; ++ni)
            acc[mi][ni] = f32x4{0.f, 0.f, 0.f, 0.f};

    const int arow = wm * 64 + l15;   // A-frag row in As
    const int brow = wn * 64 + l15;   // B-frag row in Bs
    const int swz = l15 & 7;          // row&7 for all fragment rows

    for (int k0 = 0; k0 < D_; k0 += BK) {
#pragma unroll
        for (int j = 0; j < 4; ++j) {
            load_lds16(agl + (size_t)j * 32 * D_ + k0, asl + j * 2048);
            load_lds16(bgl + (size_t)j * 32 * D_ + k0, bsl + j * 2048);
        }
        __syncthreads();   // drains vmcnt -> tiles visible

#pragma unroll
        for (int kk = 0; kk < 2; ++kk) {
            const int cba = ((kk * 4 + quad) ^ swz) * 8;  // physical chunk offset (shorts)
            bf16x8 af[4], bfr[4];
#pragma unroll
            for (int i = 0; i < 4; ++i) {
                af[i]  = *(const bf16x8*)&As[(arow + i * 16) * BK + cba];
                bfr[i] = *(const bf16x8*)&Bs[(brow + i * 16) * BK + cba];
            }
#pragma unroll
            for (int mi = 0; mi < 4; ++mi)
#pragma unroll
                for (int ni = 0; ni < 4; ++ni)
                    acc[mi][ni] = __builtin_amdgcn_mfma_f32_16x16x32_bf16(
                        af[mi], bfr[ni], acc[mi][ni], 0, 0, 0);
        }
        __syncthreads();   // all waves done reading before next overwrite
    }

    // Epilogue: C/D layout col = lane&15, row = quad*4 + reg
    const int col_base = o0 + wn * 64 + l15;
#pragma unroll
    for (int mi = 0; mi < 4; ++mi) {
#pragma unroll
        for (int reg = 0; reg < 4; ++reg) {
            const int row = t0 + wm * 64 + mi * 16 + quad * 4 + reg;
            const int idx = tli[row];
            const bool valid = (idx >= 0);
            float4 s0 = {0.f, 0.f, 0.f, 0.f}, s1 = {0.f, 0.f, 0.f, 0.f};
            if (valid) {
                s0 = *(const float4*)&shrink[row * R_];
                s1 = *(const float4*)&shrink[row * R_ + 4];
            }
#pragma unroll
            for (int ni = 0; ni < 4; ++ni) {
                const int col = col_base + ni * 16;
                float r = acc[mi][ni][reg] + base_bias[col];
                if (valid) {
                    const float* bp = &lora_b[((size_t)idx * O_ + col) * R_];
                    float4 b0 = *(const float4*)&bp[0];
                    float4 b1 = *(const float4*)&bp[4];
                    r += bias_st[(size_t)idx * O_ + col];
                    r += s0.x * b0.x + s0.y * b0.y + s0.z * b0.z + s0.w * b0.w +
                         s1.x * b1.x + s1.y * b1.y + s1.z * b1.z + s1.w * b1.w;
                }
                out[(size_t)row * O_ + col] = r;
            }
        }
    }
}

// ---------------------------------------------------------------------------
extern "C" void kernel_launch(void* const* d_in, const int* in_sizes, int n_in,
                              void* d_out, int out_size, void* d_ws, size_t ws_size,
                              hipStream_t stream) {
    const float* x    = (const float*)d_in[0];   // [T,D]
    const float* w    = (const float*)d_in[1];   // [O,D]
    const float* bb   = (const float*)d_in[2];   // [O]
    const float* la   = (const float*)d_in[3];   // [L,1,R,D]
    const float* lb   = (const float*)d_in[4];   // [L,1,O,R]
    const float* bs   = (const float*)d_in[5];   // [L,1,O]
    const int*   tli  = (const int*)d_in[6];     // [T]
    float* out = (float*)d_out;

    // workspace layout: xb (T*D bf16) | wb (O*D bf16) | shrink (T*R fp32)
    unsigned short* xb = (unsigned short*)d_ws;
    unsigned short* wb = xb + (size_t)T_ * D_;
    float* shrink = (float*)(wb + (size_t)O_ * D_);

    cvt_kernel<<<(O_ * (size_t)D_) / 1024, 256, 0, stream>>>(w, wb);
    cvtx_shrink<<<T_, 256, 0, stream>>>(x, la, tli, xb, shrink);
    gemm_lora<<<(T_ / BM) * (O_ / BN), 256, 0, stream>>>(
        (const short*)xb, (const short*)wb, bb, lb, bs, tli, shrink, out);
}